// Round 1
// baseline (1502.898 us; speedup 1.0000x reference)
//
#include <hip/hip_runtime.h>

#define B_  16
#define C_  256
#define CK_ 32
#define N_  2304   // 48*48
#define NT  32     // projection n-tile
#define TI  32     // attention i-tile (q rows per block)
#define TJ  64     // attention j-tile (k/v rows per step)

__device__ __forceinline__ float getc(const float4& v, int k){
  return k==0 ? v.x : k==1 ? v.y : k==2 ? v.z : v.w;
}
__device__ __forceinline__ void fma4(float4& a, float w, const float4& xv){
  a.x = fmaf(w, xv.x, a.x); a.y = fmaf(w, xv.y, a.y);
  a.z = fmaf(w, xv.z, a.z); a.w = fmaf(w, xv.w, a.w);
}

// ---------------------------------------------------------------------------
// Projection: q = Wq·x + bq  -> Qb[B][N][32]
//             k = Wk·x + bk  -> Kb[B][N][32]
//             v = Wv·x + bv  -> Vtb[B][N][256]  (transposed: Vt[n][c] = v[c][n])
// ---------------------------------------------------------------------------
__global__ __launch_bounds__(256) void proj_kernel(
    const float* __restrict__ x,
    const float* __restrict__ Wq, const float* __restrict__ bq,
    const float* __restrict__ Wk, const float* __restrict__ bk,
    const float* __restrict__ Wv, const float* __restrict__ bv,
    float* __restrict__ Qb, float* __restrict__ Kb, float* __restrict__ Vtb) {
  __shared__ float Xs[C_][36];           // padded: conflict-free f4 reads
  const int b   = blockIdx.x / (N_/NT);
  const int n0  = (blockIdx.x % (N_/NT)) * NT;
  const int t   = threadIdx.x;
  const int nn4 = t & 7;                 // which 4-column group (0..7)
  const int og  = t >> 3;                // output-row group (0..31)

  // stage X tile [256 c][32 n], coalesced float4 loads
  {
    const int c = t >> 3;
    #pragma unroll
    for (int p = 0; p < 8; ++p) {
      const int cc = c + p*32;
      const float4 v = *(const float4*)(x + ((size_t)b*C_ + cc)*N_ + n0 + nn4*4);
      *(float4*)(&Xs[cc][nn4*4]) = v;
    }
  }
  __syncthreads();
  const float* XsP = &Xs[0][0] + nn4*4;

  // pass 0: V rows og*8 .. og*8+7  (covers all 256 channels)
  {
    float4 acc[8];
    const float* WvP = Wv + (size_t)og*8*C_;
    #pragma unroll
    for (int oo=0;oo<8;++oo){ const float bb = bv[og*8+oo]; acc[oo] = make_float4(bb,bb,bb,bb); }
    for (int c4 = 0; c4 < C_/4; ++c4) {
      const float4 xv0 = *(const float4*)(XsP + (c4*4+0)*36);
      const float4 xv1 = *(const float4*)(XsP + (c4*4+1)*36);
      const float4 xv2 = *(const float4*)(XsP + (c4*4+2)*36);
      const float4 xv3 = *(const float4*)(XsP + (c4*4+3)*36);
      #pragma unroll
      for (int oo=0;oo<8;++oo){
        const float4 w = *(const float4*)(WvP + oo*C_ + c4*4);
        fma4(acc[oo], w.x, xv0); fma4(acc[oo], w.y, xv1);
        fma4(acc[oo], w.z, xv2); fma4(acc[oo], w.w, xv3);
      }
    }
    // store transposed: Vt[b][n][c], 8 consecutive c per thread -> two f4 stores
    #pragma unroll
    for (int k=0;k<4;++k){
      float4 lo = make_float4(getc(acc[0],k),getc(acc[1],k),getc(acc[2],k),getc(acc[3],k));
      float4 hi = make_float4(getc(acc[4],k),getc(acc[5],k),getc(acc[6],k),getc(acc[7],k));
      float* dst = Vtb + ((size_t)b*N_ + n0 + nn4*4 + k)*C_ + og*8;
      *(float4*)dst = lo; *(float4*)(dst+4) = hi;
    }
  }

  // pass 1: rows 0..63 = Q(0..31) + K(32..63); thread does rows og*2, og*2+1
  {
    const int r0 = og*2, r1 = og*2+1;
    const float* W0; const float* W1; float b0v, b1v;
    if (r0 < CK_) { W0 = Wq + r0*C_;        b0v = bq[r0]; }
    else          { W0 = Wk + (r0-CK_)*C_;  b0v = bk[r0-CK_]; }
    if (r1 < CK_) { W1 = Wq + r1*C_;        b1v = bq[r1]; }
    else          { W1 = Wk + (r1-CK_)*C_;  b1v = bk[r1-CK_]; }
    float4 a0 = make_float4(b0v,b0v,b0v,b0v), a1 = make_float4(b1v,b1v,b1v,b1v);
    for (int c4 = 0; c4 < C_/4; ++c4) {
      const float4 xv0 = *(const float4*)(XsP + (c4*4+0)*36);
      const float4 xv1 = *(const float4*)(XsP + (c4*4+1)*36);
      const float4 xv2 = *(const float4*)(XsP + (c4*4+2)*36);
      const float4 xv3 = *(const float4*)(XsP + (c4*4+3)*36);
      const float4 w0 = *(const float4*)(W0 + c4*4);
      fma4(a0, w0.x, xv0); fma4(a0, w0.y, xv1); fma4(a0, w0.z, xv2); fma4(a0, w0.w, xv3);
      const float4 w1 = *(const float4*)(W1 + c4*4);
      fma4(a1, w1.x, xv0); fma4(a1, w1.y, xv1); fma4(a1, w1.z, xv2); fma4(a1, w1.w, xv3);
    }
    float* base = (r0 < CK_) ? Qb : Kb;
    const int rr = r0 & (CK_-1);     // row pair never straddles the Q/K boundary
    #pragma unroll
    for (int k=0;k<4;++k){
      float2 st = make_float2(getc(a0,k), getc(a1,k));
      *(float2*)(base + ((size_t)b*N_ + n0 + nn4*4 + k)*CK_ + rr) = st;
    }
  }
}

// ---------------------------------------------------------------------------
// Flash attention: block = (b, 32 q-rows). Thread owns channel c = tid.
// ---------------------------------------------------------------------------
__global__ __launch_bounds__(256) void attn_kernel(
    const float* __restrict__ Qb, const float* __restrict__ Kb,
    const float* __restrict__ Vtb,
    const float* __restrict__ x, const float* __restrict__ gptr,
    float* __restrict__ out) {
  __shared__ float smem[8448];       // Qs[32][36] | Ks[64][36] | Ps[32][68]; epilogue T[256][33]
  __shared__ float m_s[TI], l_s[TI], f_s[TI];
  float* Qs = smem;
  float* Ks = smem + 1152;
  float* Ps = smem + 3456;           // byte offset 13824, 16B aligned

  const int b    = blockIdx.x / (N_/TI);
  const int i0   = (blockIdx.x % (N_/TI)) * TI;
  const int t    = threadIdx.x;
  const int sub  = t & 7;
  const int irow = t >> 3;           // 0..31

  {
    const int r = t >> 3, d4 = t & 7;
    *(float4*)(Qs + r*36 + d4*4) =
        *(const float4*)(Qb + ((size_t)b*N_ + i0 + r)*CK_ + d4*4);
  }
  if (t < TI) { m_s[t] = -1e30f; l_s[t] = 0.f; f_s[t] = 0.f; }
  float acc[TI];
  #pragma unroll
  for (int i=0;i<TI;++i) acc[i] = 0.f;
  const float* vcol = Vtb + (size_t)b*N_*C_ + t;
  __syncthreads();

  float4 q[8];
  #pragma unroll
  for (int d4=0; d4<8; ++d4) q[d4] = *(const float4*)(Qs + irow*36 + d4*4);

  for (int jt = 0; jt < N_/TJ; ++jt) {
    const int j0 = jt*TJ;
    // stage K tile [64][32]
    {
      const int r = t >> 3, d4 = t & 7;
      *(float4*)(Ks + r*36 + d4*4) =
          *(const float4*)(Kb + ((size_t)b*N_ + j0 + r)*CK_ + d4*4);
      *(float4*)(Ks + (r+32)*36 + d4*4) =
          *(const float4*)(Kb + ((size_t)b*N_ + j0 + 32 + r)*CK_ + d4*4);
    }
    __syncthreads();
    // fused scores + online softmax: thread (irow, sub) handles jj = sub+8r
    {
      float e[8]; float mloc = -1e30f;
      #pragma unroll
      for (int r=0;r<8;++r){
        const int jj = sub + 8*r;
        const float* kr = Ks + jj*36;
        float s = 0.f;
        #pragma unroll
        for (int d4=0; d4<8; ++d4){
          const float4 kv = *(const float4*)(kr + d4*4);
          s = fmaf(q[d4].x, kv.x, s); s = fmaf(q[d4].y, kv.y, s);
          s = fmaf(q[d4].z, kv.z, s); s = fmaf(q[d4].w, kv.w, s);
        }
        e[r] = s * 0.0625f;          // 1/sqrt(C)=1/16
        mloc = fmaxf(mloc, e[r]);
      }
      #pragma unroll
      for (int w=1; w<8; w<<=1) mloc = fmaxf(mloc, __shfl_xor(mloc, w));
      const float mold = m_s[irow];
      const float mnew = fmaxf(mold, mloc);
      float sum = 0.f;
      #pragma unroll
      for (int r=0;r<8;++r){
        const float p = __expf(e[r]-mnew);
        Ps[irow*68 + sub + 8*r] = p;
        sum += p;
      }
      #pragma unroll
      for (int w=1; w<8; w<<=1) sum += __shfl_xor(sum, w);
      if (sub==0){
        const float f = __expf(mold - mnew);
        l_s[irow] = l_s[irow]*f + sum;
        m_s[irow] = mnew;
        f_s[irow] = f;
      }
    }
    __syncthreads();
    // rescale + PV: acc[i] += P[i][jj] * Vt[j][c]
    {
      #pragma unroll
      for (int i=0;i<TI;++i) acc[i] *= f_s[i];
      #pragma unroll 4
      for (int jj4=0; jj4<TJ/4; ++jj4){
        const float v0 = vcol[(size_t)(j0 + jj4*4 + 0)*C_];
        const float v1 = vcol[(size_t)(j0 + jj4*4 + 1)*C_];
        const float v2 = vcol[(size_t)(j0 + jj4*4 + 2)*C_];
        const float v3 = vcol[(size_t)(j0 + jj4*4 + 3)*C_];
        #pragma unroll
        for (int i=0;i<TI;++i){
          const float4 p = *(const float4*)(Ps + i*68 + jj4*4);   // wave broadcast
          float a = acc[i];
          a = fmaf(p.x, v0, a); a = fmaf(p.y, v1, a);
          a = fmaf(p.z, v2, a); a = fmaf(p.w, v3, a);
          acc[i] = a;
        }
      }
    }
    __syncthreads();
  }

  // epilogue: normalize, scale by gamma, transpose via LDS, +x, coalesced store
  const float g = gptr[0];
  #pragma unroll
  for (int i=0;i<TI;++i) acc[i] = g * (acc[i] / l_s[i]);
  float* T = smem;                   // [256][33], conflict-free transpose
  #pragma unroll
  for (int i=0;i<TI;++i) T[t*33 + i] = acc[i];
  __syncthreads();
  {
    const int ii = t & 31, cg = t >> 5;
    #pragma unroll 4
    for (int p=0;p<32;++p){
      const int c = p*8 + cg;
      const size_t gidx = ((size_t)b*C_ + c)*N_ + i0 + ii;
      out[gidx] = T[c*33 + ii] + x[gidx];
    }
  }
}

extern "C" void kernel_launch(void* const* d_in, const int* in_sizes, int n_in,
                              void* d_out, int out_size, void* d_ws, size_t ws_size,
                              hipStream_t stream) {
  const float* x     = (const float*)d_in[0];
  const float* Wq    = (const float*)d_in[1];
  const float* bq    = (const float*)d_in[2];
  const float* Wk    = (const float*)d_in[3];
  const float* bk    = (const float*)d_in[4];
  const float* Wv    = (const float*)d_in[5];
  const float* bv    = (const float*)d_in[6];
  const float* gamma = (const float*)d_in[7];
  float* out = (float*)d_out;

  float* Qws  = (float*)d_ws;                       // [B][N][32]
  const size_t QSZ = (size_t)B_*N_*CK_;             // 1,179,648 floats
  float* Kws  = Qws + QSZ;                          // [B][N][32]
  float* Vtws = Kws + QSZ;                          // [B][N][256]

  proj_kernel<<<dim3(B_*(N_/NT)), dim3(256), 0, stream>>>(
      x, Wq, bq, Wk, bk, Wv, bv, Qws, Kws, Vtws);
  attn_kernel<<<dim3(B_*(N_/TI)), dim3(256), 0, stream>>>(
      Qws, Kws, Vtws, x, gamma, out);
}

// Round 2
// 328.538 us; speedup vs baseline: 4.5745x; 4.5745x over previous
//
#include <hip/hip_runtime.h>
#include <hip/hip_bf16.h>

#define Bn  16
#define Cn  256
#define CKn 32
#define Nn  2304   // 48*48

typedef __attribute__((ext_vector_type(16))) float f32x16;
typedef __attribute__((ext_vector_type(8)))  short bf16x8;

union FragU { unsigned u[4]; bf16x8 v; };

__device__ __forceinline__ unsigned pk(float lo, float hi){
  unsigned a = (unsigned)__bfloat16_as_ushort(__float2bfloat16(lo));
  unsigned b = (unsigned)__bfloat16_as_ushort(__float2bfloat16(hi));
  return a | (b << 16);
}

// D-layout (col=lane&31, row=(r&3)+8*(r>>2)+4h) -> A/B-frag layout (row/col=lane&31,
// k=8h+e). Packed word A holds k-pair at J, B holds J+8; outputs: w0 (k-pair 16kt+8h),
// w2 (k-pair 16kt+8h+4).
__device__ __forceinline__ void halfswap(unsigned A, unsigned Bv, int h,
                                         unsigned &w0, unsigned &w2){
  unsigned As = (unsigned)__shfl_xor((int)A, 32);
  unsigned Bs = (unsigned)__shfl_xor((int)Bv, 32);
  w0 = h ? Bs : A;
  w2 = h ? Bv : As;
}

// Convert one D-layout f32x16 tile to two bf16 frags (k=0..15, 16..31) and store.
__device__ __forceinline__ void conv_store(const f32x16& a, int h, int l,
                                           __hip_bfloat16* dst0, size_t stride){
  unsigned Wp[8];
  #pragma unroll
  for (int q = 0; q < 8; ++q) Wp[q] = pk(a[2*q], a[2*q+1]);
  #pragma unroll
  for (int k2 = 0; k2 < 2; ++k2){
    FragU u;
    halfswap(Wp[4*k2+0], Wp[4*k2+2], h, u.u[0], u.u[2]);
    halfswap(Wp[4*k2+1], Wp[4*k2+3], h, u.u[1], u.u[3]);
    *(bf16x8*)(dst0 + k2*stride + l*8) = u.v;
  }
}

// ---------------------------------------------------------------------------
// Pack weights+bias into MFMA frag layout. Wf[kt 0..16][tile 0..9][512] bf16.
// tiles 0..7: WvT (B-op: lane=c col, k=c'), 8: Wq (A-op: lane=d row), 9: Wk.
// kt==16 is the bias channel (c'==256 -> 1.0 in x-frag).
// ---------------------------------------------------------------------------
__global__ __launch_bounds__(64) void wfrag_kernel(
    const float* __restrict__ Wq, const float* __restrict__ bq,
    const float* __restrict__ Wk, const float* __restrict__ bk,
    const float* __restrict__ Wv, const float* __restrict__ bv,
    __hip_bfloat16* __restrict__ Wf){
  const int kt = blockIdx.x / 10, tile = blockIdx.x % 10;
  const int l = threadIdx.x, lo = l & 31, h = l >> 5;
  __hip_bfloat16* dst = Wf + (size_t)(kt*10 + tile)*512 + l*8;
  if (kt < 16){
    const float* Wp; int row;
    if (tile < 8)       { Wp = Wv; row = tile*32 + lo; }
    else if (tile == 8) { Wp = Wq; row = lo; }
    else                { Wp = Wk; row = lo; }
    #pragma unroll
    for (int e = 0; e < 8; ++e)
      dst[e] = __float2bfloat16(Wp[(size_t)row*Cn + kt*16 + 8*h + e]);
  } else {
    const float* bp = tile < 8 ? bv : (tile == 8 ? bq : bk);
    int row = tile < 8 ? tile*32 + lo : lo;
    #pragma unroll
    for (int e = 0; e < 8; ++e)
      dst[e] = __float2bfloat16((h == 0 && e == 0) ? bp[row] : 0.f);
  }
}

// ---------------------------------------------------------------------------
// Projection GEMM: per wave one (b, n32) unit. 10 output tiles x 17 k-steps.
// V computed transposed (mfma(xT, WvT)) so all outputs convert with halfswap.
// ---------------------------------------------------------------------------
__global__ __launch_bounds__(256) void proj_kernel(
    const float* __restrict__ x, const __hip_bfloat16* __restrict__ Wf,
    __hip_bfloat16* __restrict__ Qf, __hip_bfloat16* __restrict__ Kf,
    __hip_bfloat16* __restrict__ Vf){
  const int u = blockIdx.x*4 + (threadIdx.x >> 6);
  const int b = u / 72, n32 = u % 72;
  const int l = threadIdx.x & 63, lo = l & 31, h = l >> 5;
  const int n0 = n32*32;

  f32x16 acc[10];
  #pragma unroll
  for (int t = 0; t < 10; ++t)
    #pragma unroll
    for (int r = 0; r < 16; ++r) acc[t][r] = 0.f;

  const float* xb = x + (size_t)b*Cn*Nn + n0 + lo;

  #pragma unroll 1
  for (int kt = 0; kt < 16; ++kt){
    FragU xf;
    float v[8];
    #pragma unroll
    for (int e = 0; e < 8; ++e) v[e] = xb[(size_t)(kt*16 + 8*h + e)*Nn];
    #pragma unroll
    for (int q = 0; q < 4; ++q) xf.u[q] = pk(v[2*q], v[2*q+1]);
    const __hip_bfloat16* wfp = Wf + (size_t)(kt*10)*512 + l*8;
    #pragma unroll
    for (int t = 0; t < 10; ++t){
      bf16x8 wf = *(const bf16x8*)(wfp + t*512);
      if (t < 8) acc[t] = __builtin_amdgcn_mfma_f32_32x32x16_bf16(xf.v, wf, acc[t], 0,0,0);
      else       acc[t] = __builtin_amdgcn_mfma_f32_32x32x16_bf16(wf, xf.v, acc[t], 0,0,0);
    }
  }
  { // bias k-step: x-frag is 1.0 at c'==256 (h==0,e==0), else 0
    FragU xf;
    xf.u[0] = h ? 0u : 0x00003f80u;
    xf.u[1] = xf.u[2] = xf.u[3] = 0u;
    const __hip_bfloat16* wfp = Wf + (size_t)(16*10)*512 + l*8;
    #pragma unroll
    for (int t = 0; t < 10; ++t){
      bf16x8 wf = *(const bf16x8*)(wfp + t*512);
      if (t < 8) acc[t] = __builtin_amdgcn_mfma_f32_32x32x16_bf16(xf.v, wf, acc[t], 0,0,0);
      else       acc[t] = __builtin_amdgcn_mfma_f32_32x32x16_bf16(wf, xf.v, acc[t], 0,0,0);
    }
  }

  // V tiles: D^T[n][c] -> Vf[b][js=2*n32+kt'][ct][lane][8]
  #pragma unroll
  for (int t = 0; t < 8; ++t)
    conv_store(acc[t], h, l, Vf + (((size_t)b*144 + n32*2)*8 + t)*512, 8*512);
  // Q: D[d][n] -> Qf[b][it=n32][kt'][lane][8]   (B-operand layout)
  conv_store(acc[8], h, l, Qf + ((size_t)b*72 + n32)*2*512, 512);
  // K: -> Kf (A-operand layout)
  conv_store(acc[9], h, l, Kf + ((size_t)b*72 + n32)*2*512, 512);
}

// ---------------------------------------------------------------------------
// Attention: wave = (b, 64 q-rows, 64 v-channels). Swapped QK^T, in-register
// online softmax (defer-max THR=8), transposed PV. No LDS, no barriers.
// ---------------------------------------------------------------------------
__global__ __launch_bounds__(256) void attn_kernel(
    const __hip_bfloat16* __restrict__ Qf, const __hip_bfloat16* __restrict__ Kf,
    const __hip_bfloat16* __restrict__ Vf, const float* __restrict__ x,
    const float* __restrict__ gptr, float* __restrict__ out){
  const int b = blockIdx.x / 36, it64 = blockIdx.x % 36;
  const int w = threadIdx.x >> 6, l = threadIdx.x & 63, lo = l & 31, h = l >> 5;
  const float k1 = 0.09016844f;  // log2(e)/sqrt(C) = 1.4427/16

  bf16x8 qf[2][2];
  #pragma unroll
  for (int g = 0; g < 2; ++g)
    #pragma unroll
    for (int kt = 0; kt < 2; ++kt)
      qf[g][kt] = *(const bf16x8*)(Qf + (((size_t)b*72 + it64*2 + g)*2 + kt)*512 + l*8);

  f32x16 acc[2][2];
  #pragma unroll
  for (int g = 0; g < 2; ++g)
    #pragma unroll
    for (int ct = 0; ct < 2; ++ct)
      #pragma unroll
      for (int r = 0; r < 16; ++r) acc[g][ct][r] = 0.f;
  float m[2] = {-3.0e38f, -3.0e38f}, lsum[2] = {0.f, 0.f};

  #pragma unroll 1
  for (int jt = 0; jt < 36; ++jt){
    bf16x8 kf[2][2], vf[4][2];
    #pragma unroll
    for (int js = 0; js < 2; ++js)
      #pragma unroll
      for (int kt = 0; kt < 2; ++kt)
        kf[js][kt] = *(const bf16x8*)(Kf + (((size_t)b*72 + jt*2 + js)*2 + kt)*512 + l*8);
    #pragma unroll
    for (int js = 0; js < 4; ++js)
      #pragma unroll
      for (int ct = 0; ct < 2; ++ct)
        vf[js][ct] = *(const bf16x8*)(Vf + (((size_t)b*144 + jt*4 + js)*8 + 2*w + ct)*512 + l*8);

    #pragma unroll
    for (int g = 0; g < 2; ++g){
      f32x16 z;
      #pragma unroll
      for (int r = 0; r < 16; ++r) z[r] = 0.f;
      // S^T[j][i]: col=i=lane&31, row j=crow(r,h)+32*jsub
      f32x16 S0 = __builtin_amdgcn_mfma_f32_32x32x16_bf16(kf[0][0], qf[g][0], z, 0,0,0);
      S0 = __builtin_amdgcn_mfma_f32_32x32x16_bf16(kf[0][1], qf[g][1], S0, 0,0,0);
      f32x16 S1 = __builtin_amdgcn_mfma_f32_32x32x16_bf16(kf[1][0], qf[g][0], z, 0,0,0);
      S1 = __builtin_amdgcn_mfma_f32_32x32x16_bf16(kf[1][1], qf[g][1], S1, 0,0,0);

      float mloc = -3.0e38f;
      #pragma unroll
      for (int r = 0; r < 16; ++r) mloc = fmaxf(mloc, fmaxf(S0[r], S1[r]));
      mloc *= k1;
      mloc = fmaxf(mloc, __shfl_xor(mloc, 32));
      if (__any(mloc > m[g] + 8.f)){           // defer-max: rescale rarely
        float mnew = fmaxf(m[g], mloc);
        float f = exp2f(m[g] - mnew);
        lsum[g] *= f;
        #pragma unroll
        for (int r = 0; r < 16; ++r){ acc[g][0][r] *= f; acc[g][1][r] *= f; }
        m[g] = mnew;
      }
      unsigned Wp[16]; float sadd = 0.f;
      #pragma unroll
      for (int q = 0; q < 8; ++q){
        float p0 = exp2f(S0[2*q]*k1 - m[g]);
        float p1 = exp2f(S0[2*q+1]*k1 - m[g]);
        sadd += p0 + p1; Wp[q] = pk(p0, p1);
      }
      #pragma unroll
      for (int q = 0; q < 8; ++q){
        float p0 = exp2f(S1[2*q]*k1 - m[g]);
        float p1 = exp2f(S1[2*q+1]*k1 - m[g]);
        sadd += p0 + p1; Wp[8+q] = pk(p0, p1);
      }
      lsum[g] += sadd;

      FragU pf[4];
      #pragma unroll
      for (int js = 0; js < 4; ++js){
        int base = (js >> 1)*8 + (js & 1)*4;
        halfswap(Wp[base+0], Wp[base+2], h, pf[js].u[0], pf[js].u[2]);
        halfswap(Wp[base+1], Wp[base+3], h, pf[js].u[1], pf[js].u[3]);
      }
      // out^T[c][i] += sum_j V[j][c]? no: A=vf (row=c,k=j), B=pf (k=j,col=i)
      #pragma unroll
      for (int ct = 0; ct < 2; ++ct)
        #pragma unroll
        for (int js = 0; js < 4; ++js)
          acc[g][ct] = __builtin_amdgcn_mfma_f32_32x32x16_bf16(vf[js][ct], pf[js].v, acc[g][ct], 0,0,0);
    }
  }

  const float gam = gptr[0];
  #pragma unroll
  for (int g = 0; g < 2; ++g){
    float lf = lsum[g] + __shfl_xor(lsum[g], 32);
    float sc = gam / lf;
    #pragma unroll
    for (int ct = 0; ct < 2; ++ct)
      #pragma unroll
      for (int r = 0; r < 16; ++r){
        int c = (2*w + ct)*32 + (r & 3) + 8*(r >> 2) + 4*h;
        size_t idx = ((size_t)b*Cn + c)*Nn + (size_t)it64*64 + g*32 + lo;
        out[idx] = acc[g][ct][r]*sc + x[idx];
      }
  }
}

extern "C" void kernel_launch(void* const* d_in, const int* in_sizes, int n_in,
                              void* d_out, int out_size, void* d_ws, size_t ws_size,
                              hipStream_t stream) {
  const float* x     = (const float*)d_in[0];
  const float* Wq    = (const float*)d_in[1];
  const float* bq    = (const float*)d_in[2];
  const float* Wk    = (const float*)d_in[3];
  const float* bk    = (const float*)d_in[4];
  const float* Wv    = (const float*)d_in[5];
  const float* bv    = (const float*)d_in[6];
  const float* gamma = (const float*)d_in[7];
  float* out = (float*)d_out;

  __hip_bfloat16* Qf = (__hip_bfloat16*)d_ws;          // 16*72*2*512
  __hip_bfloat16* Kf = Qf + (size_t)Bn*72*2*512;       // + 1,179,648
  __hip_bfloat16* Vf = Kf + (size_t)Bn*72*2*512;       // 16*144*8*512
  __hip_bfloat16* Wf = Vf + (size_t)Bn*144*8*512;      // 17*10*512

  wfrag_kernel<<<dim3(170), dim3(64), 0, stream>>>(Wq, bq, Wk, bk, Wv, bv, Wf);
  proj_kernel<<<dim3(288), dim3(256), 0, stream>>>(x, Wf, Qf, Kf, Vf);
  attn_kernel<<<dim3(576), dim3(256), 0, stream>>>(Qf, Kf, Vf, x, gamma, out);
}

// Round 3
// 220.106 us; speedup vs baseline: 6.8281x; 1.4926x over previous
//
#include <hip/hip_runtime.h>
#include <hip/hip_bf16.h>

#define Bn  16
#define Cn  256
#define CKn 32
#define Nn  2304   // 48*48

typedef __attribute__((ext_vector_type(16))) float f32x16;
typedef __attribute__((ext_vector_type(8)))  short bf16x8;

union FragU { unsigned u[4]; bf16x8 v; };

__device__ __forceinline__ unsigned pk(float lo, float hi){
  unsigned a = (unsigned)__bfloat16_as_ushort(__float2bfloat16(lo));
  unsigned b = (unsigned)__bfloat16_as_ushort(__float2bfloat16(hi));
  return a | (b << 16);
}

// D-layout (col=lane&31, row=(r&3)+8*(r>>2)+4h) -> A/B-frag layout (row/col=lane&31,
// k=8h+e). Outputs: w0 (k-pair 16kt+8h), w2 (k-pair 16kt+8h+4).
__device__ __forceinline__ void halfswap(unsigned A, unsigned Bv, int h,
                                         unsigned &w0, unsigned &w2){
  unsigned As = (unsigned)__shfl_xor((int)A, 32);
  unsigned Bs = (unsigned)__shfl_xor((int)Bv, 32);
  w0 = h ? Bs : A;
  w2 = h ? Bv : As;
}

__device__ __forceinline__ void conv_store(const f32x16& a, int h, int l,
                                           __hip_bfloat16* dst0, size_t stride){
  unsigned Wp[8];
  #pragma unroll
  for (int q = 0; q < 8; ++q) Wp[q] = pk(a[2*q], a[2*q+1]);
  #pragma unroll
  for (int k2 = 0; k2 < 2; ++k2){
    FragU u;
    halfswap(Wp[4*k2+0], Wp[4*k2+2], h, u.u[0], u.u[2]);
    halfswap(Wp[4*k2+1], Wp[4*k2+3], h, u.u[1], u.u[3]);
    *(bf16x8*)(dst0 + k2*stride + l*8) = u.v;
  }
}

// ---------------------------------------------------------------------------
// Pack weights+bias into MFMA frag layout. Wf[kt 0..16][tile 0..9][512] bf16.
// ---------------------------------------------------------------------------
__global__ __launch_bounds__(64) void wfrag_kernel(
    const float* __restrict__ Wq, const float* __restrict__ bq,
    const float* __restrict__ Wk, const float* __restrict__ bk,
    const float* __restrict__ Wv, const float* __restrict__ bv,
    __hip_bfloat16* __restrict__ Wf){
  const int kt = blockIdx.x / 10, tile = blockIdx.x % 10;
  const int l = threadIdx.x, lo = l & 31, h = l >> 5;
  __hip_bfloat16* dst = Wf + (size_t)(kt*10 + tile)*512 + l*8;
  if (kt < 16){
    const float* Wp; int row;
    if (tile < 8)       { Wp = Wv; row = tile*32 + lo; }
    else if (tile == 8) { Wp = Wq; row = lo; }
    else                { Wp = Wk; row = lo; }
    #pragma unroll
    for (int e = 0; e < 8; ++e)
      dst[e] = __float2bfloat16(Wp[(size_t)row*Cn + kt*16 + 8*h + e]);
  } else {
    const float* bp = tile < 8 ? bv : (tile == 8 ? bq : bk);
    int row = tile < 8 ? tile*32 + lo : lo;
    #pragma unroll
    for (int e = 0; e < 8; ++e)
      dst[e] = __float2bfloat16((h == 0 && e == 0) ? bp[row] : 0.f);
  }
}

// ---------------------------------------------------------------------------
// Projection GEMM. Q is pre-scaled by log2(e)/sqrt(C) so attention can use
// exp2(S - m) directly.
// ---------------------------------------------------------------------------
__global__ __launch_bounds__(256) void proj_kernel(
    const float* __restrict__ x, const __hip_bfloat16* __restrict__ Wf,
    __hip_bfloat16* __restrict__ Qf, __hip_bfloat16* __restrict__ Kf,
    __hip_bfloat16* __restrict__ Vf){
  const int u = blockIdx.x*4 + (threadIdx.x >> 6);
  const int b = u / 72, n32 = u % 72;
  const int l = threadIdx.x & 63, lo = l & 31, h = l >> 5;
  const int n0 = n32*32;

  f32x16 acc[10];
  #pragma unroll
  for (int t = 0; t < 10; ++t)
    #pragma unroll
    for (int r = 0; r < 16; ++r) acc[t][r] = 0.f;

  const float* xb = x + (size_t)b*Cn*Nn + n0 + lo;

  #pragma unroll 1
  for (int kt = 0; kt < 16; ++kt){
    FragU xf;
    float v[8];
    #pragma unroll
    for (int e = 0; e < 8; ++e) v[e] = xb[(size_t)(kt*16 + 8*h + e)*Nn];
    #pragma unroll
    for (int q = 0; q < 4; ++q) xf.u[q] = pk(v[2*q], v[2*q+1]);
    const __hip_bfloat16* wfp = Wf + (size_t)(kt*10)*512 + l*8;
    #pragma unroll
    for (int t = 0; t < 10; ++t){
      bf16x8 wf = *(const bf16x8*)(wfp + t*512);
      if (t < 8) acc[t] = __builtin_amdgcn_mfma_f32_32x32x16_bf16(xf.v, wf, acc[t], 0,0,0);
      else       acc[t] = __builtin_amdgcn_mfma_f32_32x32x16_bf16(wf, xf.v, acc[t], 0,0,0);
    }
  }
  { // bias k-step
    FragU xf;
    xf.u[0] = h ? 0u : 0x00003f80u;
    xf.u[1] = xf.u[2] = xf.u[3] = 0u;
    const __hip_bfloat16* wfp = Wf + (size_t)(16*10)*512 + l*8;
    #pragma unroll
    for (int t = 0; t < 10; ++t){
      bf16x8 wf = *(const bf16x8*)(wfp + t*512);
      if (t < 8) acc[t] = __builtin_amdgcn_mfma_f32_32x32x16_bf16(xf.v, wf, acc[t], 0,0,0);
      else       acc[t] = __builtin_amdgcn_mfma_f32_32x32x16_bf16(wf, xf.v, acc[t], 0,0,0);
    }
  }

  // fold softmax scale into Q: k1 = log2(e)/sqrt(256)
  #pragma unroll
  for (int r = 0; r < 16; ++r) acc[8][r] *= 0.09016844f;

  #pragma unroll
  for (int t = 0; t < 8; ++t)
    conv_store(acc[t], h, l, Vf + (((size_t)b*144 + n32*2)*8 + t)*512, 8*512);
  conv_store(acc[8], h, l, Qf + ((size_t)b*72 + n32)*2*512, 512);
  conv_store(acc[9], h, l, Kf + ((size_t)b*72 + n32)*2*512, 512);
}

// ---------------------------------------------------------------------------
// Attention, split-KV: block = (b, 32 q-rows); wave w owns j-tiles [9w, 9w+9),
// computes softmax ONCE per P element and PV over ALL 256 channels.
// Partials merged via LDS with (m,l) rescale; epilogue fused.
// ---------------------------------------------------------------------------
__global__ __launch_bounds__(256, 2) void attn_kernel(
    const __hip_bfloat16* __restrict__ Qf, const __hip_bfloat16* __restrict__ Kf,
    const __hip_bfloat16* __restrict__ Vf, const float* __restrict__ x,
    const float* __restrict__ gptr, float* __restrict__ out){
  __shared__ float Lacc[4][64][33];      // [wave][c_local][i], conflict-free
  __shared__ float msh[128], lsh[128];
  const int b = blockIdx.x / 72, i32 = blockIdx.x % 72;
  const int w = threadIdx.x >> 6, l = threadIdx.x & 63, lo = l & 31, h = l >> 5;

  bf16x8 qf[2];
  #pragma unroll
  for (int kt = 0; kt < 2; ++kt)
    qf[kt] = *(const bf16x8*)(Qf + (((size_t)b*72 + i32)*2 + kt)*512 + l*8);

  f32x16 acc[8];
  #pragma unroll
  for (int ct = 0; ct < 8; ++ct)
    #pragma unroll
    for (int r = 0; r < 16; ++r) acc[ct][r] = 0.f;
  float m = -3.0e38f, lsum = 0.f;

  const int jt0 = w*9;
  #pragma unroll 1
  for (int jj = 0; jj < 9; ++jj){
    const int jt = jt0 + jj;
    bf16x8 kf[2][2];
    #pragma unroll
    for (int js = 0; js < 2; ++js)
      #pragma unroll
      for (int kt = 0; kt < 2; ++kt)
        kf[js][kt] = *(const bf16x8*)(Kf + (((size_t)b*72 + jt*2 + js)*2 + kt)*512 + l*8);

    f32x16 z;
    #pragma unroll
    for (int r = 0; r < 16; ++r) z[r] = 0.f;
    f32x16 S0 = __builtin_amdgcn_mfma_f32_32x32x16_bf16(kf[0][0], qf[0], z, 0,0,0);
    S0 = __builtin_amdgcn_mfma_f32_32x32x16_bf16(kf[0][1], qf[1], S0, 0,0,0);
    f32x16 S1 = __builtin_amdgcn_mfma_f32_32x32x16_bf16(kf[1][0], qf[0], z, 0,0,0);
    S1 = __builtin_amdgcn_mfma_f32_32x32x16_bf16(kf[1][1], qf[1], S1, 0,0,0);

    // tree max (S already in log2-domain thanks to pre-scaled Q)
    float tm[16];
    #pragma unroll
    for (int r = 0; r < 16; ++r) tm[r] = fmaxf(S0[r], S1[r]);
    #pragma unroll
    for (int s = 8; s > 0; s >>= 1)
      #pragma unroll
      for (int r = 0; r < s; ++r) tm[r] = fmaxf(tm[r], tm[r+s]);
    float mloc = fmaxf(tm[0], __shfl_xor(tm[0], 32));
    if (__any(mloc > m + 8.f)){          // defer-max
      float mnew = fmaxf(m, mloc);
      float f = exp2f(m - mnew);
      lsum *= f;
      #pragma unroll
      for (int ct = 0; ct < 8; ++ct)
        #pragma unroll
        for (int r = 0; r < 16; ++r) acc[ct][r] *= f;
      m = mnew;
    }

    FragU pf[4];
    float sadd0 = 0.f, sadd1 = 0.f;
    {
      unsigned Wp[8];
      #pragma unroll
      for (int q = 0; q < 8; ++q){
        float p0 = exp2f(S0[2*q]   - m);
        float p1 = exp2f(S0[2*q+1] - m);
        sadd0 += p0 + p1; Wp[q] = pk(p0, p1);
      }
      halfswap(Wp[0], Wp[2], h, pf[0].u[0], pf[0].u[2]);
      halfswap(Wp[1], Wp[3], h, pf[0].u[1], pf[0].u[3]);
      halfswap(Wp[4], Wp[6], h, pf[1].u[0], pf[1].u[2]);
      halfswap(Wp[5], Wp[7], h, pf[1].u[1], pf[1].u[3]);
    }
    {
      unsigned Wp[8];
      #pragma unroll
      for (int q = 0; q < 8; ++q){
        float p0 = exp2f(S1[2*q]   - m);
        float p1 = exp2f(S1[2*q+1] - m);
        sadd1 += p0 + p1; Wp[q] = pk(p0, p1);
      }
      halfswap(Wp[0], Wp[2], h, pf[2].u[0], pf[2].u[2]);
      halfswap(Wp[1], Wp[3], h, pf[2].u[1], pf[2].u[3]);
      halfswap(Wp[4], Wp[6], h, pf[3].u[0], pf[3].u[2]);
      halfswap(Wp[5], Wp[7], h, pf[3].u[1], pf[3].u[3]);
    }
    lsum += sadd0 + sadd1;

    const __hip_bfloat16* vbase = Vf + ((size_t)b*144 + jt*4)*8*512 + l*8;
    #pragma unroll
    for (int ct = 0; ct < 8; ++ct){
      bf16x8 v0 = *(const bf16x8*)(vbase + (0*8 + ct)*512);
      bf16x8 v1 = *(const bf16x8*)(vbase + (1*8 + ct)*512);
      bf16x8 v2 = *(const bf16x8*)(vbase + (2*8 + ct)*512);
      bf16x8 v3 = *(const bf16x8*)(vbase + (3*8 + ct)*512);
      acc[ct] = __builtin_amdgcn_mfma_f32_32x32x16_bf16(v0, pf[0].v, acc[ct], 0,0,0);
      acc[ct] = __builtin_amdgcn_mfma_f32_32x32x16_bf16(v1, pf[1].v, acc[ct], 0,0,0);
      acc[ct] = __builtin_amdgcn_mfma_f32_32x32x16_bf16(v2, pf[2].v, acc[ct], 0,0,0);
      acc[ct] = __builtin_amdgcn_mfma_f32_32x32x16_bf16(v3, pf[3].v, acc[ct], 0,0,0);
    }
  }

  // ---- cross-wave combine ----
  lsum += __shfl_xor(lsum, 32);
  if (l < 32){ msh[w*32 + lo] = m; lsh[w*32 + lo] = lsum; }
  __syncthreads();

  const float gam = gptr[0];
  float M = fmaxf(fmaxf(msh[lo], msh[32+lo]), fmaxf(msh[64+lo], msh[96+lo]));
  float fw = exp2f(m - M);                       // this wave's rescale factor
  float L = lsh[lo]      * exp2f(msh[lo]      - M)
          + lsh[32+lo]   * exp2f(msh[32+lo]   - M)
          + lsh[64+lo]   * exp2f(msh[64+lo]   - M)
          + lsh[96+lo]   * exp2f(msh[96+lo]   - M);
  const float sc = gam / L;

  #pragma unroll 1
  for (int p = 0; p < 4; ++p){
    #pragma unroll
    for (int tt = 0; tt < 2; ++tt){
      const int ct = 2*p + tt;
      #pragma unroll
      for (int r = 0; r < 16; ++r){
        const int crow = (r & 3) + 8*(r >> 2) + 4*h;
        Lacc[w][tt*32 + crow][lo] = acc[ct][r] * fw;
      }
    }
    __syncthreads();
    {
      const int i  = threadIdx.x & 31;
      const int c0 = threadIdx.x >> 5;       // 0..7
      #pragma unroll
      for (int e = 0; e < 8; ++e){
        const int cl = c0*8 + e;
        const float s = Lacc[0][cl][i] + Lacc[1][cl][i]
                      + Lacc[2][cl][i] + Lacc[3][cl][i];
        const size_t idx = ((size_t)b*Cn + p*64 + cl)*Nn + (size_t)i32*32 + i;
        out[idx] = s*sc + x[idx];
      }
    }
    __syncthreads();
  }
}

extern "C" void kernel_launch(void* const* d_in, const int* in_sizes, int n_in,
                              void* d_out, int out_size, void* d_ws, size_t ws_size,
                              hipStream_t stream) {
  const float* x     = (const float*)d_in[0];
  const float* Wq    = (const float*)d_in[1];
  const float* bq    = (const float*)d_in[2];
  const float* Wk    = (const float*)d_in[3];
  const float* bk    = (const float*)d_in[4];
  const float* Wv    = (const float*)d_in[5];
  const float* bv    = (const float*)d_in[6];
  const float* gamma = (const float*)d_in[7];
  float* out = (float*)d_out;

  __hip_bfloat16* Qf = (__hip_bfloat16*)d_ws;          // 16*72*2*512
  __hip_bfloat16* Kf = Qf + (size_t)Bn*72*2*512;
  __hip_bfloat16* Vf = Kf + (size_t)Bn*72*2*512;       // 16*144*8*512
  __hip_bfloat16* Wf = Vf + (size_t)Bn*144*8*512;      // 17*10*512

  wfrag_kernel<<<dim3(170), dim3(64), 0, stream>>>(Wq, bq, Wk, bk, Wv, bv, Wf);
  proj_kernel<<<dim3(288), dim3(256), 0, stream>>>(x, Wf, Qf, Kf, Vf);
  attn_kernel<<<dim3(1152), dim3(256), 0, stream>>>(Qf, Kf, Vf, x, gamma, out);
}

// Round 4
// 171.386 us; speedup vs baseline: 8.7691x; 1.2843x over previous
//
#include <hip/hip_runtime.h>
#include <hip/hip_bf16.h>

#define Bn  16
#define Cn  256
#define CKn 32
#define Nn  2304   // 48*48

typedef __attribute__((ext_vector_type(16))) float f32x16;
typedef __attribute__((ext_vector_type(8)))  short bf16x8;

union FragU { unsigned u[4]; bf16x8 v; };

__device__ __forceinline__ unsigned pk(float lo, float hi){
  unsigned a = (unsigned)__bfloat16_as_ushort(__float2bfloat16(lo));
  unsigned b = (unsigned)__bfloat16_as_ushort(__float2bfloat16(hi));
  return a | (b << 16);
}

// D-layout (col=lane&31, row=(r&3)+8*(r>>2)+4h) -> A/B-frag layout (row/col=lane&31,
// k=8h+e). Outputs: w0 (k-pair 16kt+8h), w2 (k-pair 16kt+8h+4).
__device__ __forceinline__ void halfswap(unsigned A, unsigned Bv, int h,
                                         unsigned &w0, unsigned &w2){
  unsigned As = (unsigned)__shfl_xor((int)A, 32);
  unsigned Bs = (unsigned)__shfl_xor((int)Bv, 32);
  w0 = h ? Bs : A;
  w2 = h ? Bv : As;
}

__device__ __forceinline__ void conv_store(const f32x16& a, int h, int l,
                                           __hip_bfloat16* dst0, size_t stride){
  unsigned Wp[8];
  #pragma unroll
  for (int q = 0; q < 8; ++q) Wp[q] = pk(a[2*q], a[2*q+1]);
  #pragma unroll
  for (int k2 = 0; k2 < 2; ++k2){
    FragU u;
    halfswap(Wp[4*k2+0], Wp[4*k2+2], h, u.u[0], u.u[2]);
    halfswap(Wp[4*k2+1], Wp[4*k2+3], h, u.u[1], u.u[3]);
    *(bf16x8*)(dst0 + k2*stride + l*8) = u.v;
  }
}

// ---------------------------------------------------------------------------
// Pack weights+bias into MFMA frag layout. Wf[kt 0..16][tile 0..9][512] bf16.
// ---------------------------------------------------------------------------
__global__ __launch_bounds__(64) void wfrag_kernel(
    const float* __restrict__ Wq, const float* __restrict__ bq,
    const float* __restrict__ Wk, const float* __restrict__ bk,
    const float* __restrict__ Wv, const float* __restrict__ bv,
    __hip_bfloat16* __restrict__ Wf){
  const int kt = blockIdx.x / 10, tile = blockIdx.x % 10;
  const int l = threadIdx.x, lo = l & 31, h = l >> 5;
  __hip_bfloat16* dst = Wf + (size_t)(kt*10 + tile)*512 + l*8;
  if (kt < 16){
    const float* Wp; int row;
    if (tile < 8)       { Wp = Wv; row = tile*32 + lo; }
    else if (tile == 8) { Wp = Wq; row = lo; }
    else                { Wp = Wk; row = lo; }
    #pragma unroll
    for (int e = 0; e < 8; ++e)
      dst[e] = __float2bfloat16(Wp[(size_t)row*Cn + kt*16 + 8*h + e]);
  } else {
    const float* bp = tile < 8 ? bv : (tile == 8 ? bq : bk);
    int row = tile < 8 ? tile*32 + lo : lo;
    #pragma unroll
    for (int e = 0; e < 8; ++e)
      dst[e] = __float2bfloat16((h == 0 && e == 0) ? bp[row] : 0.f);
  }
}

// ---------------------------------------------------------------------------
// Projection GEMM. Q is pre-scaled by log2(e)/sqrt(C).
// ---------------------------------------------------------------------------
__global__ __launch_bounds__(256) void proj_kernel(
    const float* __restrict__ x, const __hip_bfloat16* __restrict__ Wf,
    __hip_bfloat16* __restrict__ Qf, __hip_bfloat16* __restrict__ Kf,
    __hip_bfloat16* __restrict__ Vf){
  const int u = blockIdx.x*4 + (threadIdx.x >> 6);
  const int b = u / 72, n32 = u % 72;
  const int l = threadIdx.x & 63, lo = l & 31, h = l >> 5;
  const int n0 = n32*32;

  f32x16 acc[10];
  #pragma unroll
  for (int t = 0; t < 10; ++t)
    #pragma unroll
    for (int r = 0; r < 16; ++r) acc[t][r] = 0.f;

  const float* xb = x + (size_t)b*Cn*Nn + n0 + lo;

  #pragma unroll 1
  for (int kt = 0; kt < 16; ++kt){
    FragU xf;
    float v[8];
    #pragma unroll
    for (int e = 0; e < 8; ++e) v[e] = xb[(size_t)(kt*16 + 8*h + e)*Nn];
    #pragma unroll
    for (int q = 0; q < 4; ++q) xf.u[q] = pk(v[2*q], v[2*q+1]);
    const __hip_bfloat16* wfp = Wf + (size_t)(kt*10)*512 + l*8;
    #pragma unroll
    for (int t = 0; t < 10; ++t){
      bf16x8 wf = *(const bf16x8*)(wfp + t*512);
      if (t < 8) acc[t] = __builtin_amdgcn_mfma_f32_32x32x16_bf16(xf.v, wf, acc[t], 0,0,0);
      else       acc[t] = __builtin_amdgcn_mfma_f32_32x32x16_bf16(wf, xf.v, acc[t], 0,0,0);
    }
  }
  { // bias k-step
    FragU xf;
    xf.u[0] = h ? 0u : 0x00003f80u;
    xf.u[1] = xf.u[2] = xf.u[3] = 0u;
    const __hip_bfloat16* wfp = Wf + (size_t)(16*10)*512 + l*8;
    #pragma unroll
    for (int t = 0; t < 10; ++t){
      bf16x8 wf = *(const bf16x8*)(wfp + t*512);
      if (t < 8) acc[t] = __builtin_amdgcn_mfma_f32_32x32x16_bf16(xf.v, wf, acc[t], 0,0,0);
      else       acc[t] = __builtin_amdgcn_mfma_f32_32x32x16_bf16(wf, xf.v, acc[t], 0,0,0);
    }
  }

  // fold softmax scale into Q: k1 = log2(e)/sqrt(256)
  #pragma unroll
  for (int r = 0; r < 16; ++r) acc[8][r] *= 0.09016844f;

  #pragma unroll
  for (int t = 0; t < 8; ++t)
    conv_store(acc[t], h, l, Vf + (((size_t)b*144 + n32*2)*8 + t)*512, 8*512);
  conv_store(acc[8], h, l, Qf + ((size_t)b*72 + n32)*2*512, 512);
  conv_store(acc[9], h, l, Kf + ((size_t)b*72 + n32)*2*512, 512);
}

// ---------------------------------------------------------------------------
// Attention, split-KV: block = (b, 32 q-rows); wave w owns j-tiles [9w, 9w+9).
// Epilogue p-loop FULLY UNROLLED (rule #20): all acc indices compile-time
// constant so the accumulator stays in AGPRs (no scratch spill).
// ---------------------------------------------------------------------------
__global__ __launch_bounds__(256, 2) void attn_kernel(
    const __hip_bfloat16* __restrict__ Qf, const __hip_bfloat16* __restrict__ Kf,
    const __hip_bfloat16* __restrict__ Vf, const float* __restrict__ x,
    const float* __restrict__ gptr, float* __restrict__ out){
  __shared__ float Lacc[4][64][33];      // [wave][c_local][i], conflict-free
  __shared__ float msh[128], lsh[128];
  const int b = blockIdx.x / 72, i32 = blockIdx.x % 72;
  const int w = threadIdx.x >> 6, l = threadIdx.x & 63, lo = l & 31, h = l >> 5;

  bf16x8 qf[2];
  #pragma unroll
  for (int kt = 0; kt < 2; ++kt)
    qf[kt] = *(const bf16x8*)(Qf + (((size_t)b*72 + i32)*2 + kt)*512 + l*8);

  f32x16 acc[8];
  #pragma unroll
  for (int ct = 0; ct < 8; ++ct)
    #pragma unroll
    for (int r = 0; r < 16; ++r) acc[ct][r] = 0.f;
  float m = -3.0e38f, lsum = 0.f;

  const int jt0 = w*9;
  #pragma unroll 1
  for (int jj = 0; jj < 9; ++jj){
    const int jt = jt0 + jj;
    bf16x8 kf[2][2];
    #pragma unroll
    for (int js = 0; js < 2; ++js)
      #pragma unroll
      for (int kt = 0; kt < 2; ++kt)
        kf[js][kt] = *(const bf16x8*)(Kf + (((size_t)b*72 + jt*2 + js)*2 + kt)*512 + l*8);

    f32x16 z;
    #pragma unroll
    for (int r = 0; r < 16; ++r) z[r] = 0.f;
    f32x16 S0 = __builtin_amdgcn_mfma_f32_32x32x16_bf16(kf[0][0], qf[0], z, 0,0,0);
    S0 = __builtin_amdgcn_mfma_f32_32x32x16_bf16(kf[0][1], qf[1], S0, 0,0,0);
    f32x16 S1 = __builtin_amdgcn_mfma_f32_32x32x16_bf16(kf[1][0], qf[0], z, 0,0,0);
    S1 = __builtin_amdgcn_mfma_f32_32x32x16_bf16(kf[1][1], qf[1], S1, 0,0,0);

    // tree max (S already in log2-domain thanks to pre-scaled Q)
    float tm[16];
    #pragma unroll
    for (int r = 0; r < 16; ++r) tm[r] = fmaxf(S0[r], S1[r]);
    #pragma unroll
    for (int s = 8; s > 0; s >>= 1)
      #pragma unroll
      for (int r = 0; r < s; ++r) tm[r] = fmaxf(tm[r], tm[r+s]);
    float mloc = fmaxf(tm[0], __shfl_xor(tm[0], 32));
    if (__any(mloc > m + 8.f)){          // defer-max
      float mnew = fmaxf(m, mloc);
      float f = exp2f(m - mnew);
      lsum *= f;
      #pragma unroll
      for (int ct = 0; ct < 8; ++ct)
        #pragma unroll
        for (int r = 0; r < 16; ++r) acc[ct][r] *= f;
      m = mnew;
    }

    FragU pf[4];
    float sadd0 = 0.f, sadd1 = 0.f;
    {
      unsigned Wp[8];
      #pragma unroll
      for (int q = 0; q < 8; ++q){
        float p0 = exp2f(S0[2*q]   - m);
        float p1 = exp2f(S0[2*q+1] - m);
        sadd0 += p0 + p1; Wp[q] = pk(p0, p1);
      }
      halfswap(Wp[0], Wp[2], h, pf[0].u[0], pf[0].u[2]);
      halfswap(Wp[1], Wp[3], h, pf[0].u[1], pf[0].u[3]);
      halfswap(Wp[4], Wp[6], h, pf[1].u[0], pf[1].u[2]);
      halfswap(Wp[5], Wp[7], h, pf[1].u[1], pf[1].u[3]);
    }
    {
      unsigned Wp[8];
      #pragma unroll
      for (int q = 0; q < 8; ++q){
        float p0 = exp2f(S1[2*q]   - m);
        float p1 = exp2f(S1[2*q+1] - m);
        sadd1 += p0 + p1; Wp[q] = pk(p0, p1);
      }
      halfswap(Wp[0], Wp[2], h, pf[2].u[0], pf[2].u[2]);
      halfswap(Wp[1], Wp[3], h, pf[2].u[1], pf[2].u[3]);
      halfswap(Wp[4], Wp[6], h, pf[3].u[0], pf[3].u[2]);
      halfswap(Wp[5], Wp[7], h, pf[3].u[1], pf[3].u[3]);
    }
    lsum += sadd0 + sadd1;

    const __hip_bfloat16* vbase = Vf + ((size_t)b*144 + jt*4)*8*512 + l*8;
    #pragma unroll
    for (int ct = 0; ct < 8; ++ct){
      bf16x8 v0 = *(const bf16x8*)(vbase + (0*8 + ct)*512);
      bf16x8 v1 = *(const bf16x8*)(vbase + (1*8 + ct)*512);
      bf16x8 v2 = *(const bf16x8*)(vbase + (2*8 + ct)*512);
      bf16x8 v3 = *(const bf16x8*)(vbase + (3*8 + ct)*512);
      acc[ct] = __builtin_amdgcn_mfma_f32_32x32x16_bf16(v0, pf[0].v, acc[ct], 0,0,0);
      acc[ct] = __builtin_amdgcn_mfma_f32_32x32x16_bf16(v1, pf[1].v, acc[ct], 0,0,0);
      acc[ct] = __builtin_amdgcn_mfma_f32_32x32x16_bf16(v2, pf[2].v, acc[ct], 0,0,0);
      acc[ct] = __builtin_amdgcn_mfma_f32_32x32x16_bf16(v3, pf[3].v, acc[ct], 0,0,0);
    }
  }

  // ---- cross-wave combine ----
  lsum += __shfl_xor(lsum, 32);
  if (l < 32){ msh[w*32 + lo] = m; lsh[w*32 + lo] = lsum; }
  __syncthreads();

  const float gam = gptr[0];
  float M = fmaxf(fmaxf(msh[lo], msh[32+lo]), fmaxf(msh[64+lo], msh[96+lo]));
  float fw = exp2f(m - M);                       // this wave's rescale factor
  float L = lsh[lo]      * exp2f(msh[lo]      - M)
          + lsh[32+lo]   * exp2f(msh[32+lo]   - M)
          + lsh[64+lo]   * exp2f(msh[64+lo]   - M)
          + lsh[96+lo]   * exp2f(msh[96+lo]   - M);
  const float sc = gam / L;

  // FULLY UNROLLED epilogue: p is compile-time constant in every copy, so
  // acc[2*p+tt] is a static index -> no scratch (rule #20).
  #pragma unroll
  for (int p = 0; p < 4; ++p){
    #pragma unroll
    for (int tt = 0; tt < 2; ++tt){
      const int ct = 2*p + tt;
      #pragma unroll
      for (int r = 0; r < 16; ++r){
        const int crow = (r & 3) + 8*(r >> 2) + 4*h;
        Lacc[w][tt*32 + crow][lo] = acc[ct][r] * fw;
      }
    }
    __syncthreads();
    {
      const int i  = threadIdx.x & 31;
      const int c0 = threadIdx.x >> 5;       // 0..7
      #pragma unroll
      for (int e = 0; e < 8; ++e){
        const int cl = c0*8 + e;
        const float s = Lacc[0][cl][i] + Lacc[1][cl][i]
                      + Lacc[2][cl][i] + Lacc[3][cl][i];
        const size_t idx = ((size_t)b*Cn + p*64 + cl)*Nn + (size_t)i32*32 + i;
        out[idx] = s*sc + x[idx];
      }
    }
    __syncthreads();
  }
}

extern "C" void kernel_launch(void* const* d_in, const int* in_sizes, int n_in,
                              void* d_out, int out_size, void* d_ws, size_t ws_size,
                              hipStream_t stream) {
  const float* x     = (const float*)d_in[0];
  const float* Wq    = (const float*)d_in[1];
  const float* bq    = (const float*)d_in[2];
  const float* Wk    = (const float*)d_in[3];
  const float* bk    = (const float*)d_in[4];
  const float* Wv    = (const float*)d_in[5];
  const float* bv    = (const float*)d_in[6];
  const float* gamma = (const float*)d_in[7];
  float* out = (float*)d_out;

  __hip_bfloat16* Qf = (__hip_bfloat16*)d_ws;          // 16*72*2*512
  __hip_bfloat16* Kf = Qf + (size_t)Bn*72*2*512;
  __hip_bfloat16* Vf = Kf + (size_t)Bn*72*2*512;       // 16*144*8*512
  __hip_bfloat16* Wf = Vf + (size_t)Bn*144*8*512;      // 17*10*512

  wfrag_kernel<<<dim3(170), dim3(64), 0, stream>>>(Wq, bq, Wk, bk, Wv, bv, Wf);
  proj_kernel<<<dim3(288), dim3(256), 0, stream>>>(x, Wf, Qf, Kf, Vf);
  attn_kernel<<<dim3(1152), dim3(256), 0, stream>>>(Qf, Kf, Vf, x, gamma, out);
}

// Round 5
// 169.799 us; speedup vs baseline: 8.8511x; 1.0094x over previous
//
#include <hip/hip_runtime.h>
#include <hip/hip_bf16.h>

#define Bn  16
#define Cn  256
#define CKn 32
#define Nn  2304   // 48*48

typedef __attribute__((ext_vector_type(16))) float f32x16;
typedef __attribute__((ext_vector_type(8)))  short bf16x8;

union FragU { unsigned u[4]; bf16x8 v; };

__device__ __forceinline__ unsigned pk(float lo, float hi){
  unsigned a = (unsigned)__bfloat16_as_ushort(__float2bfloat16(lo));
  unsigned b = (unsigned)__bfloat16_as_ushort(__float2bfloat16(hi));
  return a | (b << 16);
}

// D-layout (col=lane&31, row=(r&3)+8*(r>>2)+4h) -> A/B-frag layout (row/col=lane&31,
// k=8h+e). Outputs: w0 (k-pair 16kt+8h), w2 (k-pair 16kt+8h+4).
__device__ __forceinline__ void halfswap(unsigned A, unsigned Bv, int h,
                                         unsigned &w0, unsigned &w2){
  unsigned As = (unsigned)__shfl_xor((int)A, 32);
  unsigned Bs = (unsigned)__shfl_xor((int)Bv, 32);
  w0 = h ? Bs : A;
  w2 = h ? Bv : As;
}

__device__ __forceinline__ void conv_store(const f32x16& a, int h, int l,
                                           __hip_bfloat16* dst0, size_t stride){
  unsigned Wp[8];
  #pragma unroll
  for (int q = 0; q < 8; ++q) Wp[q] = pk(a[2*q], a[2*q+1]);
  #pragma unroll
  for (int k2 = 0; k2 < 2; ++k2){
    FragU u;
    halfswap(Wp[4*k2+0], Wp[4*k2+2], h, u.u[0], u.u[2]);
    halfswap(Wp[4*k2+1], Wp[4*k2+3], h, u.u[1], u.u[3]);
    *(bf16x8*)(dst0 + k2*stride + l*8) = u.v;
  }
}

// ---------------------------------------------------------------------------
// Pack weights+bias into MFMA frag layout. Wf[kt 0..16][tile 0..9][512] bf16.
// ---------------------------------------------------------------------------
__global__ __launch_bounds__(64) void wfrag_kernel(
    const float* __restrict__ Wq, const float* __restrict__ bq,
    const float* __restrict__ Wk, const float* __restrict__ bk,
    const float* __restrict__ Wv, const float* __restrict__ bv,
    __hip_bfloat16* __restrict__ Wf){
  const int kt = blockIdx.x / 10, tile = blockIdx.x % 10;
  const int l = threadIdx.x, lo = l & 31, h = l >> 5;
  __hip_bfloat16* dst = Wf + (size_t)(kt*10 + tile)*512 + l*8;
  if (kt < 16){
    const float* Wp; int row;
    if (tile < 8)       { Wp = Wv; row = tile*32 + lo; }
    else if (tile == 8) { Wp = Wq; row = lo; }
    else                { Wp = Wk; row = lo; }
    #pragma unroll
    for (int e = 0; e < 8; ++e)
      dst[e] = __float2bfloat16(Wp[(size_t)row*Cn + kt*16 + 8*h + e]);
  } else {
    const float* bp = tile < 8 ? bv : (tile == 8 ? bq : bk);
    int row = tile < 8 ? tile*32 + lo : lo;
    #pragma unroll
    for (int e = 0; e < 8; ++e)
      dst[e] = __float2bfloat16((h == 0 && e == 0) ? bp[row] : 0.f);
  }
}

// ---------------------------------------------------------------------------
// Projection GEMM. Q is pre-scaled by log2(e)/sqrt(C).
// ---------------------------------------------------------------------------
__global__ __launch_bounds__(256) void proj_kernel(
    const float* __restrict__ x, const __hip_bfloat16* __restrict__ Wf,
    __hip_bfloat16* __restrict__ Qf, __hip_bfloat16* __restrict__ Kf,
    __hip_bfloat16* __restrict__ Vf){
  const int u = blockIdx.x*4 + (threadIdx.x >> 6);
  const int b = u / 72, n32 = u % 72;
  const int l = threadIdx.x & 63, lo = l & 31, h = l >> 5;
  const int n0 = n32*32;

  f32x16 acc[10];
  #pragma unroll
  for (int t = 0; t < 10; ++t)
    #pragma unroll
    for (int r = 0; r < 16; ++r) acc[t][r] = 0.f;

  const float* xb = x + (size_t)b*Cn*Nn + n0 + lo;

  #pragma unroll 1
  for (int kt = 0; kt < 16; ++kt){
    FragU xf;
    float v[8];
    #pragma unroll
    for (int e = 0; e < 8; ++e) v[e] = xb[(size_t)(kt*16 + 8*h + e)*Nn];
    #pragma unroll
    for (int q = 0; q < 4; ++q) xf.u[q] = pk(v[2*q], v[2*q+1]);
    const __hip_bfloat16* wfp = Wf + (size_t)(kt*10)*512 + l*8;
    #pragma unroll
    for (int t = 0; t < 10; ++t){
      bf16x8 wf = *(const bf16x8*)(wfp + t*512);
      if (t < 8) acc[t] = __builtin_amdgcn_mfma_f32_32x32x16_bf16(xf.v, wf, acc[t], 0,0,0);
      else       acc[t] = __builtin_amdgcn_mfma_f32_32x32x16_bf16(wf, xf.v, acc[t], 0,0,0);
    }
  }
  { // bias k-step
    FragU xf;
    xf.u[0] = h ? 0u : 0x00003f80u;
    xf.u[1] = xf.u[2] = xf.u[3] = 0u;
    const __hip_bfloat16* wfp = Wf + (size_t)(16*10)*512 + l*8;
    #pragma unroll
    for (int t = 0; t < 10; ++t){
      bf16x8 wf = *(const bf16x8*)(wfp + t*512);
      if (t < 8) acc[t] = __builtin_amdgcn_mfma_f32_32x32x16_bf16(xf.v, wf, acc[t], 0,0,0);
      else       acc[t] = __builtin_amdgcn_mfma_f32_32x32x16_bf16(wf, xf.v, acc[t], 0,0,0);
    }
  }

  // fold softmax scale into Q: k1 = log2(e)/sqrt(256)
  #pragma unroll
  for (int r = 0; r < 16; ++r) acc[8][r] *= 0.09016844f;

  #pragma unroll
  for (int t = 0; t < 8; ++t)
    conv_store(acc[t], h, l, Vf + (((size_t)b*144 + n32*2)*8 + t)*512, 8*512);
  conv_store(acc[8], h, l, Qf + ((size_t)b*72 + n32)*2*512, 512);
  conv_store(acc[9], h, l, Kf + ((size_t)b*72 + n32)*2*512, 512);
}

// ---------------------------------------------------------------------------
// Attention, split-KV + XCD-aware swizzle (T1): hardware dispatches blockIdx
// round-robin across the 8 XCDs (xcd = blk % 8). Remap so each XCD owns
// exactly 2 batches -> one batch's Kf/Vf/Qf (~1.5 MB) stays resident in that
// XCD's 4 MiB L2 and is reused by all 72 of its q-blocks.
// ---------------------------------------------------------------------------
__global__ __launch_bounds__(256, 2) void attn_kernel(
    const __hip_bfloat16* __restrict__ Qf, const __hip_bfloat16* __restrict__ Kf,
    const __hip_bfloat16* __restrict__ Vf, const float* __restrict__ x,
    const float* __restrict__ gptr, float* __restrict__ out){
  __shared__ float Lacc[4][64][33];      // [wave][c_local][i], conflict-free
  __shared__ float msh[128], lsh[128];
  const int xcd = blockIdx.x & 7, seq = blockIdx.x >> 3;   // 1152 = 8*144
  const int b   = xcd*2 + (seq / 72);                      // 2 batches per XCD
  const int i32 = seq % 72;
  const int w = threadIdx.x >> 6, l = threadIdx.x & 63, lo = l & 31, h = l >> 5;

  bf16x8 qf[2];
  #pragma unroll
  for (int kt = 0; kt < 2; ++kt)
    qf[kt] = *(const bf16x8*)(Qf + (((size_t)b*72 + i32)*2 + kt)*512 + l*8);

  f32x16 acc[8];
  #pragma unroll
  for (int ct = 0; ct < 8; ++ct)
    #pragma unroll
    for (int r = 0; r < 16; ++r) acc[ct][r] = 0.f;
  float m = -3.0e38f, lsum = 0.f;

  const int jt0 = w*9;
  #pragma unroll 1
  for (int jj = 0; jj < 9; ++jj){
    const int jt = jt0 + jj;
    bf16x8 kf[2][2];
    #pragma unroll
    for (int js = 0; js < 2; ++js)
      #pragma unroll
      for (int kt = 0; kt < 2; ++kt)
        kf[js][kt] = *(const bf16x8*)(Kf + (((size_t)b*72 + jt*2 + js)*2 + kt)*512 + l*8);

    f32x16 z;
    #pragma unroll
    for (int r = 0; r < 16; ++r) z[r] = 0.f;
    f32x16 S0 = __builtin_amdgcn_mfma_f32_32x32x16_bf16(kf[0][0], qf[0], z, 0,0,0);
    S0 = __builtin_amdgcn_mfma_f32_32x32x16_bf16(kf[0][1], qf[1], S0, 0,0,0);
    f32x16 S1 = __builtin_amdgcn_mfma_f32_32x32x16_bf16(kf[1][0], qf[0], z, 0,0,0);
    S1 = __builtin_amdgcn_mfma_f32_32x32x16_bf16(kf[1][1], qf[1], S1, 0,0,0);

    // tree max (S already in log2-domain thanks to pre-scaled Q)
    float tm[16];
    #pragma unroll
    for (int r = 0; r < 16; ++r) tm[r] = fmaxf(S0[r], S1[r]);
    #pragma unroll
    for (int s = 8; s > 0; s >>= 1)
      #pragma unroll
      for (int r = 0; r < s; ++r) tm[r] = fmaxf(tm[r], tm[r+s]);
    float mloc = fmaxf(tm[0], __shfl_xor(tm[0], 32));
    if (__any(mloc > m + 8.f)){          // defer-max
      float mnew = fmaxf(m, mloc);
      float f = exp2f(m - mnew);
      lsum *= f;
      #pragma unroll
      for (int ct = 0; ct < 8; ++ct)
        #pragma unroll
        for (int r = 0; r < 16; ++r) acc[ct][r] *= f;
      m = mnew;
    }

    FragU pf[4];
    float sadd0 = 0.f, sadd1 = 0.f;
    {
      unsigned Wp[8];
      #pragma unroll
      for (int q = 0; q < 8; ++q){
        float p0 = exp2f(S0[2*q]   - m);
        float p1 = exp2f(S0[2*q+1] - m);
        sadd0 += p0 + p1; Wp[q] = pk(p0, p1);
      }
      halfswap(Wp[0], Wp[2], h, pf[0].u[0], pf[0].u[2]);
      halfswap(Wp[1], Wp[3], h, pf[0].u[1], pf[0].u[3]);
      halfswap(Wp[4], Wp[6], h, pf[1].u[0], pf[1].u[2]);
      halfswap(Wp[5], Wp[7], h, pf[1].u[1], pf[1].u[3]);
    }
    {
      unsigned Wp[8];
      #pragma unroll
      for (int q = 0; q < 8; ++q){
        float p0 = exp2f(S1[2*q]   - m);
        float p1 = exp2f(S1[2*q+1] - m);
        sadd1 += p0 + p1; Wp[q] = pk(p0, p1);
      }
      halfswap(Wp[0], Wp[2], h, pf[2].u[0], pf[2].u[2]);
      halfswap(Wp[1], Wp[3], h, pf[2].u[1], pf[2].u[3]);
      halfswap(Wp[4], Wp[6], h, pf[3].u[0], pf[3].u[2]);
      halfswap(Wp[5], Wp[7], h, pf[3].u[1], pf[3].u[3]);
    }
    lsum += sadd0 + sadd1;

    const __hip_bfloat16* vbase = Vf + ((size_t)b*144 + jt*4)*8*512 + l*8;
    #pragma unroll
    for (int ct = 0; ct < 8; ++ct){
      bf16x8 v0 = *(const bf16x8*)(vbase + (0*8 + ct)*512);
      bf16x8 v1 = *(const bf16x8*)(vbase + (1*8 + ct)*512);
      bf16x8 v2 = *(const bf16x8*)(vbase + (2*8 + ct)*512);
      bf16x8 v3 = *(const bf16x8*)(vbase + (3*8 + ct)*512);
      acc[ct] = __builtin_amdgcn_mfma_f32_32x32x16_bf16(v0, pf[0].v, acc[ct], 0,0,0);
      acc[ct] = __builtin_amdgcn_mfma_f32_32x32x16_bf16(v1, pf[1].v, acc[ct], 0,0,0);
      acc[ct] = __builtin_amdgcn_mfma_f32_32x32x16_bf16(v2, pf[2].v, acc[ct], 0,0,0);
      acc[ct] = __builtin_amdgcn_mfma_f32_32x32x16_bf16(v3, pf[3].v, acc[ct], 0,0,0);
    }
  }

  // ---- cross-wave combine ----
  lsum += __shfl_xor(lsum, 32);
  if (l < 32){ msh[w*32 + lo] = m; lsh[w*32 + lo] = lsum; }
  __syncthreads();

  const float gam = gptr[0];
  float M = fmaxf(fmaxf(msh[lo], msh[32+lo]), fmaxf(msh[64+lo], msh[96+lo]));
  float fw = exp2f(m - M);                       // this wave's rescale factor
  float L = lsh[lo]      * exp2f(msh[lo]      - M)
          + lsh[32+lo]   * exp2f(msh[32+lo]   - M)
          + lsh[64+lo]   * exp2f(msh[64+lo]   - M)
          + lsh[96+lo]   * exp2f(msh[96+lo]   - M);
  const float sc = gam / L;

  // fully unrolled epilogue (static acc indices, rule #20)
  #pragma unroll
  for (int p = 0; p < 4; ++p){
    #pragma unroll
    for (int tt = 0; tt < 2; ++tt){
      const int ct = 2*p + tt;
      #pragma unroll
      for (int r = 0; r < 16; ++r){
        const int crow = (r & 3) + 8*(r >> 2) + 4*h;
        Lacc[w][tt*32 + crow][lo] = acc[ct][r] * fw;
      }
    }
    __syncthreads();
    {
      const int i  = threadIdx.x & 31;
      const int c0 = threadIdx.x >> 5;       // 0..7
      #pragma unroll
      for (int e = 0; e < 8; ++e){
        const int cl = c0*8 + e;
        const float s = Lacc[0][cl][i] + Lacc[1][cl][i]
                      + Lacc[2][cl][i] + Lacc[3][cl][i];
        const size_t idx = ((size_t)b*Cn + p*64 + cl)*Nn + (size_t)i32*32 + i;
        out[idx] = s*sc + x[idx];
      }
    }
    __syncthreads();
  }
}

extern "C" void kernel_launch(void* const* d_in, const int* in_sizes, int n_in,
                              void* d_out, int out_size, void* d_ws, size_t ws_size,
                              hipStream_t stream) {
  const float* x     = (const float*)d_in[0];
  const float* Wq    = (const float*)d_in[1];
  const float* bq    = (const float*)d_in[2];
  const float* Wk    = (const float*)d_in[3];
  const float* bk    = (const float*)d_in[4];
  const float* Wv    = (const float*)d_in[5];
  const float* bv    = (const float*)d_in[6];
  const float* gamma = (const float*)d_in[7];
  float* out = (float*)d_out;

  __hip_bfloat16* Qf = (__hip_bfloat16*)d_ws;          // 16*72*2*512
  __hip_bfloat16* Kf = Qf + (size_t)Bn*72*2*512;
  __hip_bfloat16* Vf = Kf + (size_t)Bn*72*2*512;       // 16*144*8*512
  __hip_bfloat16* Wf = Vf + (size_t)Bn*144*8*512;      // 17*10*512

  wfrag_kernel<<<dim3(170), dim3(64), 0, stream>>>(Wq, bq, Wk, bk, Wv, bv, Wf);
  proj_kernel<<<dim3(288), dim3(256), 0, stream>>>(x, Wf, Qf, Kf, Vf);
  attn_kernel<<<dim3(1152), dim3(256), 0, stream>>>(Qf, Kf, Vf, x, gamma, out);
}